// Round 16
// baseline (358.628 us; speedup 1.0000x reference)
//
#include <hip/hip_runtime.h>

// Problem constants
#define B_   64
#define N_   256
#define E_   1024
#define H_   16
#define D_   64
#define S_   257
#define M_   16448      // B_*S_
#define MP2  16640      // padded to 65*256 (=130*128)
#define N3_  3072
#define K_   1024

typedef unsigned short u16;
typedef unsigned int   u32;
typedef __bf16 bf16x8 __attribute__((ext_vector_type(8)));
typedef float  f32x4  __attribute__((ext_vector_type(4)));

__device__ inline u16 f2bf(float f) {
  union { float f; u32 u; } a; a.f = f;
  return (u16)((a.u + 0x7FFFu + ((a.u >> 16) & 1u)) >> 16);
}
__device__ inline float bf2f(u16 h) {
  union { u32 u; float f; } a; a.u = ((u32)h) << 16; return a.f;
}
__device__ inline void gload_lds16(const void* g, void* l) {
  __builtin_amdgcn_global_load_lds((const __attribute__((address_space(1))) void*)g,
                                   (__attribute__((address_space(3))) void*)l, 16, 0, 0);
}

// ---------------- prep: convert in_proj_w (3E x E) f32 -> bf16 ----------------
__global__ __launch_bounds__(256) void prep_w(const float* __restrict__ w, u16* __restrict__ o) {
  size_t i = ((size_t)blockIdx.x * 256 + threadIdx.x) * 4;
  float4 f = *(const float4*)(w + i);
  ushort4 v;
  v.x = f2bf(f.x); v.y = f2bf(f.y); v.z = f2bf(f.z); v.w = f2bf(f.w);
  *(ushort4*)(o + i) = v;
}

// ---------------- build x = concat(cls, news) + pos_emb, bf16, padded rows zeroed ----------------
__global__ __launch_bounds__(256) void build_x(const float* __restrict__ news,
                                               const float* __restrict__ cls,
                                               const float* __restrict__ pos,
                                               u16* __restrict__ x) {
  const int row = blockIdx.x;          // 0..16639
  const int e = threadIdx.x * 4;
  float4 v = make_float4(0.f, 0.f, 0.f, 0.f);
  if (row < M_) {
    const int b = row / S_;
    const int s = row - b * S_;
    float4 pe = *(const float4*)(pos + (size_t)s * E_ + e);
    float4 xv = (s == 0) ? *(const float4*)(cls + e)
                         : *(const float4*)(news + ((size_t)b * N_ + (s - 1)) * E_ + e);
    v.x = xv.x + pe.x; v.y = xv.y + pe.y; v.z = xv.z + pe.z; v.w = xv.w + pe.w;
  }
  ushort4 o;
  o.x = f2bf(v.x); o.y = f2bf(v.y); o.z = f2bf(v.z); o.w = f2bf(v.w);
  *(ushort4*)(x + (size_t)row * E_ + e) = o;
}

// ---------------- mask: detect dtype (int32 / uint8 / float32) -> int32 ----------------
__global__ __launch_bounds__(256) void mask_prep(const void* __restrict__ src, int* __restrict__ dst) {
  const int t = threadIdx.x;
  const u32* wsrc = (const u32*)src;
  u32 flag = 0;
  for (int i = t; i < 4096; i += 256) {       // detection window (same for all blocks)
    u32 v = wsrc[i];
    if (v == 0x3F800000u) flag |= 2u;
    else if (v > 1u) flag |= 1u;
  }
  __shared__ u32 fsh;
  if (t == 0) fsh = 0;
  __syncthreads();
  if (flag) atomicOr(&fsh, flag);
  __syncthreads();
  const u32 f = fsh;
  const int mode = (f & 2u) ? 2 : ((f & 1u) ? 1 : 0);
  const int base = blockIdx.x * 2048;
  for (int i = base + t; i < base + 2048; i += 256) {
    int m;
    if (mode == 0)      m = (wsrc[i] != 0u);
    else if (mode == 2) m = (((const float*)src)[i] != 0.f);
    else                m = (((const unsigned char*)src)[i] != 0);
    dst[i] = m;
  }
}

// ---------------- QKV GEMM: R9 measured-best (R3 body + XCD swizzle), verbatim ----------------
// 6/6 redesigns lost to this simple 128x128x32 row-major 2-__syncthreads loop at
// natural VGPR (~84) with bijective XCD swizzle. Do not touch.
__global__ __launch_bounds__(256) void gemm_qkv(const u16* __restrict__ A,
                                                const u16* __restrict__ Bw,
                                                const float* __restrict__ bias,
                                                u16* __restrict__ C) {
  __shared__ u16 As[128 * 32];
  __shared__ u16 Bs[128 * 32];
  const int t = threadIdx.x;
  const int w = t >> 6, l = t & 63;
  const int wr = w >> 1, wc = w & 1;

  const int orig = blockIdx.x;
  const int wgid = (orig & 7) * 390 + (orig >> 3);
  const int bm = wgid / 24, bn = wgid % 24;

  const u16* Ab = A + (size_t)bm * 128 * K_;
  const u16* Bb = Bw + (size_t)bn * 128 * K_;
  f32x4 acc[4][4] = {};
  const int r0 = t >> 2,         col0 = (t & 3) << 3;
  const int r1 = (256 + t) >> 2, col1 = ((256 + t) & 3) << 3;
  char* AsB = (char*)As + w * 1024;
  char* BsB = (char*)Bs + w * 1024;

  for (int k0 = 0; k0 < K_; k0 += 32) {
    gload_lds16(Ab + (size_t)r0 * K_ + k0 + col0, AsB);
    gload_lds16(Ab + (size_t)r1 * K_ + k0 + col1, AsB + 4096);
    gload_lds16(Bb + (size_t)r0 * K_ + k0 + col0, BsB);
    gload_lds16(Bb + (size_t)r1 * K_ + k0 + col1, BsB + 4096);
    __syncthreads();
    const int kc = (l >> 4) << 3;
    bf16x8 af[4], bfr[4];
#pragma unroll
    for (int m = 0; m < 4; ++m)
      af[m] = *(const bf16x8*)&As[(wr * 64 + m * 16 + (l & 15)) * 32 + kc];
#pragma unroll
    for (int n = 0; n < 4; ++n)
      bfr[n] = *(const bf16x8*)&Bs[(wc * 64 + n * 16 + (l & 15)) * 32 + kc];
#pragma unroll
    for (int m = 0; m < 4; ++m)
#pragma unroll
      for (int n = 0; n < 4; ++n)
        acc[m][n] = __builtin_amdgcn_mfma_f32_16x16x32_bf16(af[m], bfr[n], acc[m][n], 0, 0, 0);
    __syncthreads();
  }
  const int row0 = bm * 128 + wr * 64 + ((l >> 4) << 2);
  const int colb = bn * 128 + wc * 64 + (l & 15);
#pragma unroll
  for (int n = 0; n < 4; ++n) {
    const int col = colb + n * 16;
    const float bv = bias[col];
#pragma unroll
    for (int m = 0; m < 4; ++m) {
      const int row = row0 + m * 16;
#pragma unroll
      for (int j = 0; j < 4; ++j)
        C[(size_t)(row + j) * N3_ + col] = f2bf(acc[m][n][j] + bv);
    }
  }
}

// ---------------- attention: SWAPPED MFMA + bf16-PACKED single pass ----------------
// Combines R15's pk[17][2] register diet (no spill, no recompute) with R10's swapped
// operand order: mfma(A=K-tile, B=Q-rows) puts D[row=k, col=q] -> lane (rg,cl) owns
// q-row q0+w*16+cl at k = kt*16+rg*4+j (CONSECUTIVE). Stores: 17 float4 + 1 scalar
// per lane (was 68 scalars). Row sum needs only 2 shfl_xor (16,32). Sum accumulates
// the bf16-ROUNDED values so each stored row normalizes to exactly 1.
__global__ __launch_bounds__(256) void attn_kernel(const u16* __restrict__ qkv,
                                                   const int* __restrict__ maskw,
                                                   float* __restrict__ attn,
                                                   float* __restrict__ ctx) {
  __shared__ u16 Ks[258 * 72];     // 37.2 KB (row 257 zeroed = clamp target)
  __shared__ float msk[272];       // keep-multiplier: 1=keep, 0=drop
  __shared__ float p0[272];        // normalized CLS row (qt==0 only)
  __shared__ float red[4][64];
  const int qt = blockIdx.x, h = blockIdx.y, b = blockIdx.z;
  const int t = threadIdx.x;
  const int q0 = qt * 64;

  // stage K rows 0..257 (row 257 zeroed)
  for (int c = t; c < 258 * 8; c += 256) {
    const int r = c >> 3, qq = c & 7;
    uint4 val = make_uint4(0, 0, 0, 0);
    if (r < S_)
      val = *(const uint4*)(qkv + (size_t)(b * S_ + r) * N3_ + E_ + h * 64 + qq * 8);
    *(uint4*)&Ks[r * 72 + qq * 8] = val;
  }
  // mask multipliers — ALL 272 entries (cols >= S_ must be 0)
  for (int i = t; i < 272; i += 256) {
    float m = 0.f;
    if (i == 0) m = 1.f;
    else if (i < S_) m = maskw[b * N_ + i - 1] ? 0.f : 1.f;
    msk[i] = m;
  }
  __syncthreads();

  const int w = t >> 6, l = t & 63;
  const int cl = l & 15, rg = l >> 4;
  const int kc = rg * 8;

  // B-operand: this lane's Q row (loop-invariant) straight from global.
  const u16* qrow = qkv + (size_t)(b * S_ + q0 + w * 16 + cl) * N3_ + h * 64 + kc;
  const bf16x8 qb0 = *(const bf16x8*)qrow;
  const bf16x8 qb1 = *(const bf16x8*)(qrow + 32);

  // ---- single pass: QK^T(swapped) -> exp -> round-to-bf16 -> pack; sum ROUNDED ----
  u32 pk[17][2];                   // 34 VGPR
  float sum = 0.f;
#pragma unroll
  for (int kt = 0; kt < 17; ++kt) {
    int krow = kt * 16 + cl;
    if (krow > 257) krow = 257;
    const u16* kb = &Ks[krow * 72 + kc];
    f32x4 a = {0.f, 0.f, 0.f, 0.f};
    a = __builtin_amdgcn_mfma_f32_16x16x32_bf16(*(const bf16x8*)kb, qb0, a, 0, 0, 0);
    a = __builtin_amdgcn_mfma_f32_16x16x32_bf16(*(const bf16x8*)(kb + 32), qb1, a, 0, 0, 0);
    const f32x4 m4 = *(const f32x4*)&msk[kt * 16 + rg * 4];
    u16 h0[4];
#pragma unroll
    for (int j = 0; j < 4; ++j) {
      h0[j] = f2bf(m4[j] * __expf(a[j] * 0.125f));
      sum += bf2f(h0[j]);
    }
    pk[kt][0] = (u32)h0[0] | ((u32)h0[1] << 16);
    pk[kt][1] = (u32)h0[2] | ((u32)h0[3] << 16);
  }
  sum += __shfl_xor(sum, 16);
  sum += __shfl_xor(sum, 32);
  const float inv = 1.f / sum;

  // ---- unpack, scale, store: 16 float4 + 1 scalar per lane ----
  const int gq = q0 + w * 16 + cl;
  const bool ok = (gq < S_);
  float* arow = attn + (size_t)((b * H_ + h) * S_ + gq) * S_;
  const bool isCls = (qt == 0 && w == 0 && cl == 0);
#pragma unroll
  for (int kt = 0; kt < 17; ++kt) {
    f32x4 v;
    v[0] = bf2f((u16)(pk[kt][0] & 0xFFFFu)) * inv;
    v[1] = bf2f((u16)(pk[kt][0] >> 16)) * inv;
    v[2] = bf2f((u16)(pk[kt][1] & 0xFFFFu)) * inv;
    v[3] = bf2f((u16)(pk[kt][1] >> 16)) * inv;
    if (ok) {
      if (kt < 16)       __builtin_memcpy(arow + kt * 16 + rg * 4, &v, 16);
      else if (rg == 0)  arow[256] = v[0];          // kt=16: only k=256 valid
    }
    if (isCls) {                                     // 4 rg lanes cover all 272 cols
#pragma unroll
      for (int j = 0; j < 4; ++j) p0[kt * 16 + rg * 4 + j] = v[j];  // masked -> 0
    }
  }

  // PV for the CLS row only (qt==0 blocks)
  if (qt == 0) {
    __syncthreads();
    const int part = t >> 6, d = t & 63;
    float acc = 0.f;
    for (int k = part; k < S_; k += 4)
      acc = fmaf(p0[k], bf2f(qkv[(size_t)(b * S_ + k) * N3_ + 2 * E_ + h * 64 + d]), acc);
    red[part][d] = acc;
    __syncthreads();
    if (t < 64)
      ctx[(size_t)b * E_ + h * 64 + t] = red[0][t] + red[1][t] + red[2][t] + red[3][t];
  }
}

// ---------------- GEMV for CLS rows: 256 blocks (full-chip), quad-per-row ----------------
__global__ __launch_bounds__(256) void gemv_cls(const float* __restrict__ in,
                                                const float* __restrict__ W,
                                                const float* __restrict__ bias,
                                                float* __restrict__ out) {
  const int bt = blockIdx.x, fc = blockIdx.y, t = threadIdx.x;
  __shared__ float xs[4][E_];
  for (int i = t; i < E_; i += 256)
    ((float4*)xs)[i] = ((const float4*)(in + (size_t)bt * 4 * E_))[i];
  __syncthreads();
  const int f = fc * 64 + (t >> 2);
  const int ec = (t & 3) * 256;
  const float4* wr = (const float4*)(W + (size_t)f * E_ + ec);
  float a0 = 0.f, a1 = 0.f, a2 = 0.f, a3 = 0.f;
#pragma unroll 8
  for (int e4 = 0; e4 < 64; ++e4) {
    const float4 wv = wr[e4];
    const float4 x0 = *(const float4*)&xs[0][ec + e4 * 4];
    const float4 x1 = *(const float4*)&xs[1][ec + e4 * 4];
    const float4 x2 = *(const float4*)&xs[2][ec + e4 * 4];
    const float4 x3 = *(const float4*)&xs[3][ec + e4 * 4];
    a0 += wv.x * x0.x + wv.y * x0.y + wv.z * x0.z + wv.w * x0.w;
    a1 += wv.x * x1.x + wv.y * x1.y + wv.z * x1.z + wv.w * x1.w;
    a2 += wv.x * x2.x + wv.y * x2.y + wv.z * x2.z + wv.w * x2.w;
    a3 += wv.x * x3.x + wv.y * x3.y + wv.z * x3.z + wv.w * x3.w;
  }
  a0 += __shfl_xor(a0, 1); a0 += __shfl_xor(a0, 2);
  a1 += __shfl_xor(a1, 1); a1 += __shfl_xor(a1, 2);
  a2 += __shfl_xor(a2, 1); a2 += __shfl_xor(a2, 2);
  a3 += __shfl_xor(a3, 1); a3 += __shfl_xor(a3, 2);
  if ((t & 3) == 0) {
    const float bv = bias[f];
    out[(size_t)(bt * 4 + 0) * E_ + f] = a0 + bv;
    out[(size_t)(bt * 4 + 1) * E_ + f] = a1 + bv;
    out[(size_t)(bt * 4 + 2) * E_ + f] = a2 + bv;
    out[(size_t)(bt * 4 + 3) * E_ + f] = a3 + bv;
  }
}

// ---------------- LayerNorm + ReLU + L2-normalize for the 64 CLS rows ----------------
__global__ __launch_bounds__(256) void ln_relu_norm(const float* __restrict__ p,
                                                    const float* __restrict__ gamma,
                                                    const float* __restrict__ beta,
                                                    float* __restrict__ user) {
  const int b = blockIdx.x, t = threadIdx.x;
  const int w = t >> 6, l = t & 63;
  const float4 v = ((const float4*)(p + (size_t)b * E_))[t];
  float s = v.x + v.y + v.z + v.w;
  float s2 = v.x * v.x + v.y * v.y + v.z * v.z + v.w * v.w;
#pragma unroll
  for (int o = 1; o < 64; o <<= 1) { s += __shfl_xor(s, o); s2 += __shfl_xor(s2, o); }
  __shared__ float ss[4], ss2[4], qs[4];
  if (l == 0) { ss[w] = s; ss2[w] = s2; }
  __syncthreads();
  s = ss[0] + ss[1] + ss[2] + ss[3];
  s2 = ss2[0] + ss2[1] + ss2[2] + ss2[3];
  const float mu = s * (1.f / E_);
  const float var = s2 * (1.f / E_) - mu * mu;
  const float rstd = rsqrtf(var + 1e-5f);
  const float4 g = ((const float4*)gamma)[t];
  const float4 be = ((const float4*)beta)[t];
  float4 o;
  o.x = fmaxf((v.x - mu) * rstd * g.x + be.x, 0.f);
  o.y = fmaxf((v.y - mu) * rstd * g.y + be.y, 0.f);
  o.z = fmaxf((v.z - mu) * rstd * g.z + be.z, 0.f);
  o.w = fmaxf((v.w - mu) * rstd * g.w + be.w, 0.f);
  float q2 = o.x * o.x + o.y * o.y + o.z * o.z + o.w * o.w;
#pragma unroll
  for (int off = 1; off < 64; off <<= 1) q2 += __shfl_xor(q2, off);
  if (l == 0) qs[w] = q2;
  __syncthreads();
  q2 = qs[0] + qs[1] + qs[2] + qs[3];
  const float nrm = fmaxf(sqrtf(q2), 1e-12f);
  const float inv = 1.f / nrm;
  float4 u;
  u.x = o.x * inv; u.y = o.y * inv; u.z = o.z * inv; u.w = o.w * inv;
  ((float4*)(user + (size_t)b * E_))[t] = u;
}

extern "C" void kernel_launch(void* const* d_in, const int* in_sizes, int n_in,
                              void* d_out, int out_size, void* d_ws, size_t ws_size,
                              hipStream_t stream) {
  const float* news   = (const float*)d_in[0];
  const void*  maskp  = d_in[1];
  const float* cls    = (const float*)d_in[2];
  const float* pos    = (const float*)d_in[3];
  const float* w_in   = (const float*)d_in[4];
  const float* b_in   = (const float*)d_in[5];
  const float* w_out  = (const float*)d_in[6];
  const float* b_out  = (const float*)d_in[7];
  const float* w_proj = (const float*)d_in[8];
  const float* b_proj = (const float*)d_in[9];
  const float* gamma  = (const float*)d_in[10];
  const float* beta   = (const float*)d_in[11];

  char* ws = (char*)d_ws;
  // workspace layout (total ~143.5 MB)
  u16*  w_bf  = (u16*)(ws + 0);             //   6,291,456 B  (in_proj_w bf16)
  u16*  x_bf  = (u16*)(ws + 6291456);       //  34,078,720 B  (x bf16, MP2 x E_)
  u16*  qkv   = (u16*)(ws + 40370176);      // 102,236,160 B  (qkv bf16, MP2 x 3E)
  float* ctx  = (float*)(ws + 142606336);   //     262,144 B
  float* aoc  = (float*)(ws + 142868480);   //     262,144 B
  float* pcls = (float*)(ws + 143130624);   //     262,144 B
  int*  maskw = (int*)(ws + 143392768);     //      65,536 B

  float* user = (float*)d_out;
  float* attn = (float*)d_out + (size_t)B_ * E_;

  prep_w<<<3072, 256, 0, stream>>>(w_in, w_bf);
  build_x<<<MP2, 256, 0, stream>>>(news, cls, pos, x_bf);
  mask_prep<<<8, 256, 0, stream>>>(maskp, maskw);
  gemm_qkv<<<3120, 256, 0, stream>>>(x_bf, w_bf, b_in, qkv);
  attn_kernel<<<dim3(5, H_, B_), 256, 0, stream>>>(qkv, maskw, attn, ctx);
  gemv_cls<<<dim3(16, 16), 256, 0, stream>>>(ctx, w_out, b_out, aoc);
  gemv_cls<<<dim3(16, 16), 256, 0, stream>>>(aoc, w_proj, b_proj, pcls);
  ln_relu_norm<<<B_, 256, 0, stream>>>(pcls, gamma, beta, user);
}

// Round 17
// 352.802 us; speedup vs baseline: 1.0165x; 1.0165x over previous
//
#include <hip/hip_runtime.h>

// Problem constants
#define B_   64
#define N_   256
#define E_   1024
#define H_   16
#define D_   64
#define S_   257
#define M_   16448      // B_*S_
#define MP2  16640      // padded to 65*256 (=130*128)
#define N3_  3072
#define K_   1024

typedef unsigned short u16;
typedef unsigned int   u32;
typedef __bf16 bf16x8 __attribute__((ext_vector_type(8)));
typedef float  f32x4  __attribute__((ext_vector_type(4)));

__device__ inline u16 f2bf(float f) {
  union { float f; u32 u; } a; a.f = f;
  return (u16)((a.u + 0x7FFFu + ((a.u >> 16) & 1u)) >> 16);
}
__device__ inline float bf2f(u16 h) {
  union { u32 u; float f; } a; a.u = ((u32)h) << 16; return a.f;
}
__device__ inline void gload_lds16(const void* g, void* l) {
  __builtin_amdgcn_global_load_lds((const __attribute__((address_space(1))) void*)g,
                                   (__attribute__((address_space(3))) void*)l, 16, 0, 0);
}

// ---------------- prep: convert in_proj_w (3E x E) f32 -> bf16 ----------------
__global__ __launch_bounds__(256) void prep_w(const float* __restrict__ w, u16* __restrict__ o) {
  size_t i = ((size_t)blockIdx.x * 256 + threadIdx.x) * 4;
  float4 f = *(const float4*)(w + i);
  ushort4 v;
  v.x = f2bf(f.x); v.y = f2bf(f.y); v.z = f2bf(f.z); v.w = f2bf(f.w);
  *(ushort4*)(o + i) = v;
}

// ---------------- build x = concat(cls, news) + pos_emb, bf16, padded rows zeroed ----------------
__global__ __launch_bounds__(256) void build_x(const float* __restrict__ news,
                                               const float* __restrict__ cls,
                                               const float* __restrict__ pos,
                                               u16* __restrict__ x) {
  const int row = blockIdx.x;          // 0..16639
  const int e = threadIdx.x * 4;
  float4 v = make_float4(0.f, 0.f, 0.f, 0.f);
  if (row < M_) {
    const int b = row / S_;
    const int s = row - b * S_;
    float4 pe = *(const float4*)(pos + (size_t)s * E_ + e);
    float4 xv = (s == 0) ? *(const float4*)(cls + e)
                         : *(const float4*)(news + ((size_t)b * N_ + (s - 1)) * E_ + e);
    v.x = xv.x + pe.x; v.y = xv.y + pe.y; v.z = xv.z + pe.z; v.w = xv.w + pe.w;
  }
  ushort4 o;
  o.x = f2bf(v.x); o.y = f2bf(v.y); o.z = f2bf(v.z); o.w = f2bf(v.w);
  *(ushort4*)(x + (size_t)row * E_ + e) = o;
}

// ---------------- mask: detect dtype (int32 / uint8 / float32) -> int32 ----------------
__global__ __launch_bounds__(256) void mask_prep(const void* __restrict__ src, int* __restrict__ dst) {
  const int t = threadIdx.x;
  const u32* wsrc = (const u32*)src;
  u32 flag = 0;
  for (int i = t; i < 4096; i += 256) {       // detection window (same for all blocks)
    u32 v = wsrc[i];
    if (v == 0x3F800000u) flag |= 2u;
    else if (v > 1u) flag |= 1u;
  }
  __shared__ u32 fsh;
  if (t == 0) fsh = 0;
  __syncthreads();
  if (flag) atomicOr(&fsh, flag);
  __syncthreads();
  const u32 f = fsh;
  const int mode = (f & 2u) ? 2 : ((f & 1u) ? 1 : 0);
  const int base = blockIdx.x * 2048;
  for (int i = base + t; i < base + 2048; i += 256) {
    int m;
    if (mode == 0)      m = (wsrc[i] != 0u);
    else if (mode == 2) m = (((const float*)src)[i] != 0.f);
    else                m = (((const unsigned char*)src)[i] != 0);
    dst[i] = m;
  }
}

// ---------------- QKV GEMM: R9 measured-best (R3 body + XCD swizzle), verbatim ----------------
// 6/6 redesigns lost to this simple 128x128x32 row-major 2-__syncthreads loop at
// natural VGPR (~84) with bijective XCD swizzle. Do not touch.
__global__ __launch_bounds__(256) void gemm_qkv(const u16* __restrict__ A,
                                                const u16* __restrict__ Bw,
                                                const float* __restrict__ bias,
                                                u16* __restrict__ C) {
  __shared__ u16 As[128 * 32];
  __shared__ u16 Bs[128 * 32];
  const int t = threadIdx.x;
  const int w = t >> 6, l = t & 63;
  const int wr = w >> 1, wc = w & 1;

  const int orig = blockIdx.x;
  const int wgid = (orig & 7) * 390 + (orig >> 3);
  const int bm = wgid / 24, bn = wgid % 24;

  const u16* Ab = A + (size_t)bm * 128 * K_;
  const u16* Bb = Bw + (size_t)bn * 128 * K_;
  f32x4 acc[4][4] = {};
  const int r0 = t >> 2,         col0 = (t & 3) << 3;
  const int r1 = (256 + t) >> 2, col1 = ((256 + t) & 3) << 3;
  char* AsB = (char*)As + w * 1024;
  char* BsB = (char*)Bs + w * 1024;

  for (int k0 = 0; k0 < K_; k0 += 32) {
    gload_lds16(Ab + (size_t)r0 * K_ + k0 + col0, AsB);
    gload_lds16(Ab + (size_t)r1 * K_ + k0 + col1, AsB + 4096);
    gload_lds16(Bb + (size_t)r0 * K_ + k0 + col0, BsB);
    gload_lds16(Bb + (size_t)r1 * K_ + k0 + col1, BsB + 4096);
    __syncthreads();
    const int kc = (l >> 4) << 3;
    bf16x8 af[4], bfr[4];
#pragma unroll
    for (int m = 0; m < 4; ++m)
      af[m] = *(const bf16x8*)&As[(wr * 64 + m * 16 + (l & 15)) * 32 + kc];
#pragma unroll
    for (int n = 0; n < 4; ++n)
      bfr[n] = *(const bf16x8*)&Bs[(wc * 64 + n * 16 + (l & 15)) * 32 + kc];
#pragma unroll
    for (int m = 0; m < 4; ++m)
#pragma unroll
      for (int n = 0; n < 4; ++n)
        acc[m][n] = __builtin_amdgcn_mfma_f32_16x16x32_bf16(af[m], bfr[n], acc[m][n], 0, 0, 0);
    __syncthreads();
  }
  const int row0 = bm * 128 + wr * 64 + ((l >> 4) << 2);
  const int colb = bn * 128 + wc * 64 + (l & 15);
#pragma unroll
  for (int n = 0; n < 4; ++n) {
    const int col = colb + n * 16;
    const float bv = bias[col];
#pragma unroll
    for (int m = 0; m < 4; ++m) {
      const int row = row0 + m * 16;
#pragma unroll
      for (int j = 0; j < 4; ++j)
        C[(size_t)(row + j) * N3_ + col] = f2bf(acc[m][n][j] + bv);
    }
  }
}

// ---------------- attention: R15 champion (bf16-packed single pass) + XCD swizzle ----------------
// R15 structure verbatim (non-swapped MFMA, pk[17][2] bf16-packed scores, sum of
// ROUNDED values -> rows normalize to exactly 1). ONE change (T1): 1D grid 5120 with
// bijective XCD chunk-swizzle (5120 = 8 x 640) so the 5 qt-sibling blocks of each
// (b,h) — which stage the SAME 33KB K panel — land on the same XCD -> K staging
// becomes an L2 hit for 4 of 5 blocks.
__global__ __launch_bounds__(256) void attn_kernel(const u16* __restrict__ qkv,
                                                   const int* __restrict__ maskw,
                                                   float* __restrict__ attn,
                                                   float* __restrict__ ctx) {
  __shared__ u16 Ks[258 * 72];     // 37.2 KB (row 257 zeroed = clamp target)
  __shared__ float msk[272];       // keep-multiplier: 1=keep, 0=drop
  __shared__ float p0[272];        // normalized CLS row (qt==0 only)
  __shared__ float red[4][64];
  // bijective XCD swizzle: each XCD gets a contiguous chunk of 640 block ids;
  // qt fastest -> all 5 blocks of one (b,h) share an XCD (K panel L2-resident)
  const int orig = blockIdx.x;
  const int wgid = (orig & 7) * 640 + (orig >> 3);
  const int qt = wgid % 5;
  const int hb = wgid / 5;
  const int h = hb & 15, b = hb >> 4;
  const int t = threadIdx.x;
  const int q0 = qt * 64;

  // stage K rows 0..257 (row 257 zeroed)
  for (int c = t; c < 258 * 8; c += 256) {
    const int r = c >> 3, qq = c & 7;
    uint4 val = make_uint4(0, 0, 0, 0);
    if (r < S_)
      val = *(const uint4*)(qkv + (size_t)(b * S_ + r) * N3_ + E_ + h * 64 + qq * 8);
    *(uint4*)&Ks[r * 72 + qq * 8] = val;
  }
  // mask multipliers — ALL 272 entries (cols >= S_ must be 0)
  for (int i = t; i < 272; i += 256) {
    float m = 0.f;
    if (i == 0) m = 1.f;
    else if (i < S_) m = maskw[b * N_ + i - 1] ? 0.f : 1.f;
    msk[i] = m;
  }
  __syncthreads();

  const int w = t >> 6, l = t & 63;
  const int cl = l & 15, rg = l >> 4;
  const int kc = rg * 8;

  // Q fragment (loop-invariant) straight from global; row b*S_+q0+w*16+cl < MP2 rows
  const u16* qrow = qkv + (size_t)(b * S_ + q0 + w * 16 + cl) * N3_ + h * 64 + kc;
  const bf16x8 qa0 = *(const bf16x8*)qrow;
  const bf16x8 qa1 = *(const bf16x8*)(qrow + 32);

  // ---- single pass: QK -> exp -> round-to-bf16 -> pack; sum the ROUNDED values ----
  u32 pk[17][2];                   // 34 VGPR: 4 bf16 exp values per kt tile
  float sum[4] = {0.f, 0.f, 0.f, 0.f};
#pragma unroll
  for (int kt = 0; kt < 17; ++kt) {
    int krow = kt * 16 + cl;
    if (krow > 257) krow = 257;
    const u16* kb = &Ks[krow * 72 + kc];
    f32x4 a = {0.f, 0.f, 0.f, 0.f};
    a = __builtin_amdgcn_mfma_f32_16x16x32_bf16(qa0, *(const bf16x8*)kb, a, 0, 0, 0);
    a = __builtin_amdgcn_mfma_f32_16x16x32_bf16(qa1, *(const bf16x8*)(kb + 32), a, 0, 0, 0);
    const float m = msk[kt * 16 + cl];
    u16 h0[4];
#pragma unroll
    for (int j = 0; j < 4; ++j) {
      h0[j] = f2bf(m * __expf(a[j] * 0.125f));
      sum[j] += bf2f(h0[j]);                       // sum of rounded values
    }
    pk[kt][0] = (u32)h0[0] | ((u32)h0[1] << 16);
    pk[kt][1] = (u32)h0[2] | ((u32)h0[3] << 16);
  }
  float inv[4];
#pragma unroll
  for (int j = 0; j < 4; ++j) {
#pragma unroll
    for (int o = 1; o < 16; o <<= 1) sum[j] += __shfl_xor(sum[j], o);
    inv[j] = 1.f / sum[j];
  }

  // ---- unpack, scale, store ----
  const int qrow0 = q0 + w * 16 + rg * 4;
  float* abase = attn + (size_t)(b * H_ + h) * S_ * S_;
  const bool isCls = (qt == 0 && w == 0 && rg == 0);
#pragma unroll
  for (int j = 0; j < 4; ++j) {
    const int gq = qrow0 + j;
    if (gq < S_) {
      float* arow = abase + (size_t)gq * S_;
#pragma unroll
      for (int kt = 0; kt < 17; ++kt) {
        const int col = kt * 16 + cl;
        if (col < S_) {
          const u16 hh = (u16)(pk[kt][j >> 1] >> ((j & 1) * 16));
          arow[col] = bf2f(hh) * inv[j];
        }
      }
    }
  }
  if (isCls) {
#pragma unroll
    for (int kt = 0; kt < 17; ++kt) {
      const u16 hh = (u16)(pk[kt][0] & 0xFFFFu);   // j==0 value
      p0[kt * 16 + cl] = bf2f(hh) * inv[0];        // masked/pad cols -> 0
    }
  }

  // PV for the CLS row only (qt==0 blocks)
  if (qt == 0) {
    __syncthreads();
    const int part = t >> 6, d = t & 63;
    float acc = 0.f;
    for (int k = part; k < S_; k += 4)
      acc = fmaf(p0[k], bf2f(qkv[(size_t)(b * S_ + k) * N3_ + 2 * E_ + h * 64 + d]), acc);
    red[part][d] = acc;
    __syncthreads();
    if (t < 64)
      ctx[(size_t)b * E_ + h * 64 + t] = red[0][t] + red[1][t] + red[2][t] + red[3][t];
  }
}

// ---------------- GEMV for CLS rows: 256 blocks (full-chip), quad-per-row ----------------
__global__ __launch_bounds__(256) void gemv_cls(const float* __restrict__ in,
                                                const float* __restrict__ W,
                                                const float* __restrict__ bias,
                                                float* __restrict__ out) {
  const int bt = blockIdx.x, fc = blockIdx.y, t = threadIdx.x;
  __shared__ float xs[4][E_];
  for (int i = t; i < E_; i += 256)
    ((float4*)xs)[i] = ((const float4*)(in + (size_t)bt * 4 * E_))[i];
  __syncthreads();
  const int f = fc * 64 + (t >> 2);
  const int ec = (t & 3) * 256;
  const float4* wr = (const float4*)(W + (size_t)f * E_ + ec);
  float a0 = 0.f, a1 = 0.f, a2 = 0.f, a3 = 0.f;
#pragma unroll 8
  for (int e4 = 0; e4 < 64; ++e4) {
    const float4 wv = wr[e4];
    const float4 x0 = *(const float4*)&xs[0][ec + e4 * 4];
    const float4 x1 = *(const float4*)&xs[1][ec + e4 * 4];
    const float4 x2 = *(const float4*)&xs[2][ec + e4 * 4];
    const float4 x3 = *(const float4*)&xs[3][ec + e4 * 4];
    a0 += wv.x * x0.x + wv.y * x0.y + wv.z * x0.z + wv.w * x0.w;
    a1 += wv.x * x1.x + wv.y * x1.y + wv.z * x1.z + wv.w * x1.w;
    a2 += wv.x * x2.x + wv.y * x2.y + wv.z * x2.z + wv.w * x2.w;
    a3 += wv.x * x3.x + wv.y * x3.y + wv.z * x3.z + wv.w * x3.w;
  }
  a0 += __shfl_xor(a0, 1); a0 += __shfl_xor(a0, 2);
  a1 += __shfl_xor(a1, 1); a1 += __shfl_xor(a1, 2);
  a2 += __shfl_xor(a2, 1); a2 += __shfl_xor(a2, 2);
  a3 += __shfl_xor(a3, 1); a3 += __shfl_xor(a3, 2);
  if ((t & 3) == 0) {
    const float bv = bias[f];
    out[(size_t)(bt * 4 + 0) * E_ + f] = a0 + bv;
    out[(size_t)(bt * 4 + 1) * E_ + f] = a1 + bv;
    out[(size_t)(bt * 4 + 2) * E_ + f] = a2 + bv;
    out[(size_t)(bt * 4 + 3) * E_ + f] = a3 + bv;
  }
}

// ---------------- LayerNorm + ReLU + L2-normalize for the 64 CLS rows ----------------
__global__ __launch_bounds__(256) void ln_relu_norm(const float* __restrict__ p,
                                                    const float* __restrict__ gamma,
                                                    const float* __restrict__ beta,
                                                    float* __restrict__ user) {
  const int b = blockIdx.x, t = threadIdx.x;
  const int w = t >> 6, l = t & 63;
  const float4 v = ((const float4*)(p + (size_t)b * E_))[t];
  float s = v.x + v.y + v.z + v.w;
  float s2 = v.x * v.x + v.y * v.y + v.z * v.z + v.w * v.w;
#pragma unroll
  for (int o = 1; o < 64; o <<= 1) { s += __shfl_xor(s, o); s2 += __shfl_xor(s2, o); }
  __shared__ float ss[4], ss2[4], qs[4];
  if (l == 0) { ss[w] = s; ss2[w] = s2; }
  __syncthreads();
  s = ss[0] + ss[1] + ss[2] + ss[3];
  s2 = ss2[0] + ss2[1] + ss2[2] + ss2[3];
  const float mu = s * (1.f / E_);
  const float var = s2 * (1.f / E_) - mu * mu;
  const float rstd = rsqrtf(var + 1e-5f);
  const float4 g = ((const float4*)gamma)[t];
  const float4 be = ((const float4*)beta)[t];
  float4 o;
  o.x = fmaxf((v.x - mu) * rstd * g.x + be.x, 0.f);
  o.y = fmaxf((v.y - mu) * rstd * g.y + be.y, 0.f);
  o.z = fmaxf((v.z - mu) * rstd * g.z + be.z, 0.f);
  o.w = fmaxf((v.w - mu) * rstd * g.w + be.w, 0.f);
  float q2 = o.x * o.x + o.y * o.y + o.z * o.z + o.w * o.w;
#pragma unroll
  for (int off = 1; off < 64; off <<= 1) q2 += __shfl_xor(q2, off);
  if (l == 0) qs[w] = q2;
  __syncthreads();
  q2 = qs[0] + qs[1] + qs[2] + qs[3];
  const float nrm = fmaxf(sqrtf(q2), 1e-12f);
  const float inv = 1.f / nrm;
  float4 u;
  u.x = o.x * inv; u.y = o.y * inv; u.z = o.z * inv; u.w = o.w * inv;
  ((float4*)(user + (size_t)b * E_))[t] = u;
}

extern "C" void kernel_launch(void* const* d_in, const int* in_sizes, int n_in,
                              void* d_out, int out_size, void* d_ws, size_t ws_size,
                              hipStream_t stream) {
  const float* news   = (const float*)d_in[0];
  const void*  maskp  = d_in[1];
  const float* cls    = (const float*)d_in[2];
  const float* pos    = (const float*)d_in[3];
  const float* w_in   = (const float*)d_in[4];
  const float* b_in   = (const float*)d_in[5];
  const float* w_out  = (const float*)d_in[6];
  const float* b_out  = (const float*)d_in[7];
  const float* w_proj = (const float*)d_in[8];
  const float* b_proj = (const float*)d_in[9];
  const float* gamma  = (const float*)d_in[10];
  const float* beta   = (const float*)d_in[11];

  char* ws = (char*)d_ws;
  // workspace layout (total ~143.5 MB)
  u16*  w_bf  = (u16*)(ws + 0);             //   6,291,456 B  (in_proj_w bf16)
  u16*  x_bf  = (u16*)(ws + 6291456);       //  34,078,720 B  (x bf16, MP2 x E_)
  u16*  qkv   = (u16*)(ws + 40370176);      // 102,236,160 B  (qkv bf16, MP2 x 3E)
  float* ctx  = (float*)(ws + 142606336);   //     262,144 B
  float* aoc  = (float*)(ws + 142868480);   //     262,144 B
  float* pcls = (float*)(ws + 143130624);   //     262,144 B
  int*  maskw = (int*)(ws + 143392768);     //      65,536 B

  float* user = (float*)d_out;
  float* attn = (float*)d_out + (size_t)B_ * E_;

  prep_w<<<3072, 256, 0, stream>>>(w_in, w_bf);
  build_x<<<MP2, 256, 0, stream>>>(news, cls, pos, x_bf);
  mask_prep<<<8, 256, 0, stream>>>(maskp, maskw);
  gemm_qkv<<<3120, 256, 0, stream>>>(x_bf, w_bf, b_in, qkv);
  attn_kernel<<<5120, 256, 0, stream>>>(qkv, maskw, attn, ctx);
  gemv_cls<<<dim3(16, 16), 256, 0, stream>>>(ctx, w_out, b_out, aoc);
  gemv_cls<<<dim3(16, 16), 256, 0, stream>>>(aoc, w_proj, b_proj, pcls);
  ln_relu_norm<<<B_, 256, 0, stream>>>(pcls, gamma, beta, user);
}

// Round 18
// 348.268 us; speedup vs baseline: 1.0297x; 1.0130x over previous
//
#include <hip/hip_runtime.h>

// Problem constants
#define B_   64
#define N_   256
#define E_   1024
#define H_   16
#define D_   64
#define S_   257
#define M_   16448      // B_*S_
#define MP2  16640      // padded to 65*256 (=130*128)
#define N3_  3072
#define K_   1024

typedef unsigned short u16;
typedef unsigned int   u32;
typedef __bf16 bf16x8 __attribute__((ext_vector_type(8)));
typedef float  f32x4  __attribute__((ext_vector_type(4)));

__device__ inline u16 f2bf(float f) {
  union { float f; u32 u; } a; a.f = f;
  return (u16)((a.u + 0x7FFFu + ((a.u >> 16) & 1u)) >> 16);
}
__device__ inline float bf2f(u16 h) {
  union { u32 u; float f; } a; a.u = ((u32)h) << 16; return a.f;
}
__device__ inline void gload_lds16(const void* g, void* l) {
  __builtin_amdgcn_global_load_lds((const __attribute__((address_space(1))) void*)g,
                                   (__attribute__((address_space(3))) void*)l, 16, 0, 0);
}

// ---------------- prep: convert in_proj_w (3E x E) f32 -> bf16 ----------------
__global__ __launch_bounds__(256) void prep_w(const float* __restrict__ w, u16* __restrict__ o) {
  size_t i = ((size_t)blockIdx.x * 256 + threadIdx.x) * 4;
  float4 f = *(const float4*)(w + i);
  ushort4 v;
  v.x = f2bf(f.x); v.y = f2bf(f.y); v.z = f2bf(f.z); v.w = f2bf(f.w);
  *(ushort4*)(o + i) = v;
}

// ---------------- build x = concat(cls, news) + pos_emb, bf16, padded rows zeroed ----------------
__global__ __launch_bounds__(256) void build_x(const float* __restrict__ news,
                                               const float* __restrict__ cls,
                                               const float* __restrict__ pos,
                                               u16* __restrict__ x) {
  const int row = blockIdx.x;          // 0..16639
  const int e = threadIdx.x * 4;
  float4 v = make_float4(0.f, 0.f, 0.f, 0.f);
  if (row < M_) {
    const int b = row / S_;
    const int s = row - b * S_;
    float4 pe = *(const float4*)(pos + (size_t)s * E_ + e);
    float4 xv = (s == 0) ? *(const float4*)(cls + e)
                         : *(const float4*)(news + ((size_t)b * N_ + (s - 1)) * E_ + e);
    v.x = xv.x + pe.x; v.y = xv.y + pe.y; v.z = xv.z + pe.z; v.w = xv.w + pe.w;
  }
  ushort4 o;
  o.x = f2bf(v.x); o.y = f2bf(v.y); o.z = f2bf(v.z); o.w = f2bf(v.w);
  *(ushort4*)(x + (size_t)row * E_ + e) = o;
}

// ---------------- mask: detect dtype (int32 / uint8 / float32) -> int32 ----------------
__global__ __launch_bounds__(256) void mask_prep(const void* __restrict__ src, int* __restrict__ dst) {
  const int t = threadIdx.x;
  const u32* wsrc = (const u32*)src;
  u32 flag = 0;
  for (int i = t; i < 4096; i += 256) {       // detection window (same for all blocks)
    u32 v = wsrc[i];
    if (v == 0x3F800000u) flag |= 2u;
    else if (v > 1u) flag |= 1u;
  }
  __shared__ u32 fsh;
  if (t == 0) fsh = 0;
  __syncthreads();
  if (flag) atomicOr(&fsh, flag);
  __syncthreads();
  const u32 f = fsh;
  const int mode = (f & 2u) ? 2 : ((f & 1u) ? 1 : 0);
  const int base = blockIdx.x * 2048;
  for (int i = base + t; i < base + 2048; i += 256) {
    int m;
    if (mode == 0)      m = (wsrc[i] != 0u);
    else if (mode == 2) m = (((const float*)src)[i] != 0.f);
    else                m = (((const unsigned char*)src)[i] != 0);
    dst[i] = m;
  }
}

// ---------------- QKV GEMM: R9 measured-best (R3 body + XCD swizzle), verbatim ----------------
// 6/6 redesigns lost to this simple 128x128x32 row-major 2-__syncthreads loop at
// natural VGPR (~84) with bijective XCD swizzle. Do not touch.
__global__ __launch_bounds__(256) void gemm_qkv(const u16* __restrict__ A,
                                                const u16* __restrict__ Bw,
                                                const float* __restrict__ bias,
                                                u16* __restrict__ C) {
  __shared__ u16 As[128 * 32];
  __shared__ u16 Bs[128 * 32];
  const int t = threadIdx.x;
  const int w = t >> 6, l = t & 63;
  const int wr = w >> 1, wc = w & 1;

  const int orig = blockIdx.x;
  const int wgid = (orig & 7) * 390 + (orig >> 3);
  const int bm = wgid / 24, bn = wgid % 24;

  const u16* Ab = A + (size_t)bm * 128 * K_;
  const u16* Bb = Bw + (size_t)bn * 128 * K_;
  f32x4 acc[4][4] = {};
  const int r0 = t >> 2,         col0 = (t & 3) << 3;
  const int r1 = (256 + t) >> 2, col1 = ((256 + t) & 3) << 3;
  char* AsB = (char*)As + w * 1024;
  char* BsB = (char*)Bs + w * 1024;

  for (int k0 = 0; k0 < K_; k0 += 32) {
    gload_lds16(Ab + (size_t)r0 * K_ + k0 + col0, AsB);
    gload_lds16(Ab + (size_t)r1 * K_ + k0 + col1, AsB + 4096);
    gload_lds16(Bb + (size_t)r0 * K_ + k0 + col0, BsB);
    gload_lds16(Bb + (size_t)r1 * K_ + k0 + col1, BsB + 4096);
    __syncthreads();
    const int kc = (l >> 4) << 3;
    bf16x8 af[4], bfr[4];
#pragma unroll
    for (int m = 0; m < 4; ++m)
      af[m] = *(const bf16x8*)&As[(wr * 64 + m * 16 + (l & 15)) * 32 + kc];
#pragma unroll
    for (int n = 0; n < 4; ++n)
      bfr[n] = *(const bf16x8*)&Bs[(wc * 64 + n * 16 + (l & 15)) * 32 + kc];
#pragma unroll
    for (int m = 0; m < 4; ++m)
#pragma unroll
      for (int n = 0; n < 4; ++n)
        acc[m][n] = __builtin_amdgcn_mfma_f32_16x16x32_bf16(af[m], bfr[n], acc[m][n], 0, 0, 0);
    __syncthreads();
  }
  const int row0 = bm * 128 + wr * 64 + ((l >> 4) << 2);
  const int colb = bn * 128 + wc * 64 + (l & 15);
#pragma unroll
  for (int n = 0; n < 4; ++n) {
    const int col = colb + n * 16;
    const float bv = bias[col];
#pragma unroll
    for (int m = 0; m < 4; ++m) {
      const int row = row0 + m * 16;
#pragma unroll
      for (int j = 0; j < 4; ++j)
        C[(size_t)(row + j) * N3_ + col] = f2bf(acc[m][n][j] + bv);
    }
  }
}

// ---------------- attention: R15 champion — bf16-packed single pass, default dispatch ----------
// Non-swapped MFMA (scalar stores coalesce to 4x64B segments/instr — swapped float4
// scatters across 64 rows and lost twice). pk[17][2] bf16-packed scores (34 VGPR, no
// scratch spill, no recompute). Sum accumulates the ROUNDED values so each stored row
// normalizes to exactly 1. Ks 258 rows stride 72 (row 257 zeroed = clamp target for
// the kt=16 tail); Q fragments straight from global (rows >= S_ are in-bounds pad).
// R17's XCD swizzle was neutral-negative (K panels are L3-served already) — reverted.
__global__ __launch_bounds__(256) void attn_kernel(const u16* __restrict__ qkv,
                                                   const int* __restrict__ maskw,
                                                   float* __restrict__ attn,
                                                   float* __restrict__ ctx) {
  __shared__ u16 Ks[258 * 72];     // 37.2 KB
  __shared__ float msk[272];       // keep-multiplier: 1=keep, 0=drop
  __shared__ float p0[272];        // normalized CLS row (qt==0 only)
  __shared__ float red[4][64];
  const int qt = blockIdx.x, h = blockIdx.y, b = blockIdx.z;
  const int t = threadIdx.x;
  const int q0 = qt * 64;

  // stage K rows 0..257 (row 257 zeroed)
  for (int c = t; c < 258 * 8; c += 256) {
    const int r = c >> 3, qq = c & 7;
    uint4 val = make_uint4(0, 0, 0, 0);
    if (r < S_)
      val = *(const uint4*)(qkv + (size_t)(b * S_ + r) * N3_ + E_ + h * 64 + qq * 8);
    *(uint4*)&Ks[r * 72 + qq * 8] = val;
  }
  // mask multipliers — ALL 272 entries (cols >= S_ must be 0)
  for (int i = t; i < 272; i += 256) {
    float m = 0.f;
    if (i == 0) m = 1.f;
    else if (i < S_) m = maskw[b * N_ + i - 1] ? 0.f : 1.f;
    msk[i] = m;
  }
  __syncthreads();

  const int w = t >> 6, l = t & 63;
  const int cl = l & 15, rg = l >> 4;
  const int kc = rg * 8;

  // Q fragment (loop-invariant) straight from global; row b*S_+q0+w*16+cl < MP2 rows
  const u16* qrow = qkv + (size_t)(b * S_ + q0 + w * 16 + cl) * N3_ + h * 64 + kc;
  const bf16x8 qa0 = *(const bf16x8*)qrow;
  const bf16x8 qa1 = *(const bf16x8*)(qrow + 32);

  // ---- single pass: QK -> exp -> round-to-bf16 -> pack; sum the ROUNDED values ----
  u32 pk[17][2];                   // 34 VGPR: 4 bf16 exp values per kt tile
  float sum[4] = {0.f, 0.f, 0.f, 0.f};
#pragma unroll
  for (int kt = 0; kt < 17; ++kt) {
    int krow = kt * 16 + cl;
    if (krow > 257) krow = 257;
    const u16* kb = &Ks[krow * 72 + kc];
    f32x4 a = {0.f, 0.f, 0.f, 0.f};
    a = __builtin_amdgcn_mfma_f32_16x16x32_bf16(qa0, *(const bf16x8*)kb, a, 0, 0, 0);
    a = __builtin_amdgcn_mfma_f32_16x16x32_bf16(qa1, *(const bf16x8*)(kb + 32), a, 0, 0, 0);
    const float m = msk[kt * 16 + cl];
    u16 h0[4];
#pragma unroll
    for (int j = 0; j < 4; ++j) {
      h0[j] = f2bf(m * __expf(a[j] * 0.125f));
      sum[j] += bf2f(h0[j]);                       // sum of rounded values
    }
    pk[kt][0] = (u32)h0[0] | ((u32)h0[1] << 16);
    pk[kt][1] = (u32)h0[2] | ((u32)h0[3] << 16);
  }
  float inv[4];
#pragma unroll
  for (int j = 0; j < 4; ++j) {
#pragma unroll
    for (int o = 1; o < 16; o <<= 1) sum[j] += __shfl_xor(sum[j], o);
    inv[j] = 1.f / sum[j];
  }

  // ---- unpack, scale, store ----
  const int qrow0 = q0 + w * 16 + rg * 4;
  float* abase = attn + (size_t)(b * H_ + h) * S_ * S_;
  const bool isCls = (qt == 0 && w == 0 && rg == 0);
#pragma unroll
  for (int j = 0; j < 4; ++j) {
    const int gq = qrow0 + j;
    if (gq < S_) {
      float* arow = abase + (size_t)gq * S_;
#pragma unroll
      for (int kt = 0; kt < 17; ++kt) {
        const int col = kt * 16 + cl;
        if (col < S_) {
          const u16 hh = (u16)(pk[kt][j >> 1] >> ((j & 1) * 16));
          arow[col] = bf2f(hh) * inv[j];
        }
      }
    }
  }
  if (isCls) {
#pragma unroll
    for (int kt = 0; kt < 17; ++kt) {
      const u16 hh = (u16)(pk[kt][0] & 0xFFFFu);   // j==0 value
      p0[kt * 16 + cl] = bf2f(hh) * inv[0];        // masked/pad cols -> 0
    }
  }

  // PV for the CLS row only (qt==0 blocks)
  if (qt == 0) {
    __syncthreads();
    const int part = t >> 6, d = t & 63;
    float acc = 0.f;
    for (int k = part; k < S_; k += 4)
      acc = fmaf(p0[k], bf2f(qkv[(size_t)(b * S_ + k) * N3_ + 2 * E_ + h * 64 + d]), acc);
    red[part][d] = acc;
    __syncthreads();
    if (t < 64)
      ctx[(size_t)b * E_ + h * 64 + t] = red[0][t] + red[1][t] + red[2][t] + red[3][t];
  }
}

// ---------------- GEMV for CLS rows: 256 blocks (full-chip), quad-per-row ----------------
__global__ __launch_bounds__(256) void gemv_cls(const float* __restrict__ in,
                                                const float* __restrict__ W,
                                                const float* __restrict__ bias,
                                                float* __restrict__ out) {
  const int bt = blockIdx.x, fc = blockIdx.y, t = threadIdx.x;
  __shared__ float xs[4][E_];
  for (int i = t; i < E_; i += 256)
    ((float4*)xs)[i] = ((const float4*)(in + (size_t)bt * 4 * E_))[i];
  __syncthreads();
  const int f = fc * 64 + (t >> 2);
  const int ec = (t & 3) * 256;
  const float4* wr = (const float4*)(W + (size_t)f * E_ + ec);
  float a0 = 0.f, a1 = 0.f, a2 = 0.f, a3 = 0.f;
#pragma unroll 8
  for (int e4 = 0; e4 < 64; ++e4) {
    const float4 wv = wr[e4];
    const float4 x0 = *(const float4*)&xs[0][ec + e4 * 4];
    const float4 x1 = *(const float4*)&xs[1][ec + e4 * 4];
    const float4 x2 = *(const float4*)&xs[2][ec + e4 * 4];
    const float4 x3 = *(const float4*)&xs[3][ec + e4 * 4];
    a0 += wv.x * x0.x + wv.y * x0.y + wv.z * x0.z + wv.w * x0.w;
    a1 += wv.x * x1.x + wv.y * x1.y + wv.z * x1.z + wv.w * x1.w;
    a2 += wv.x * x2.x + wv.y * x2.y + wv.z * x2.z + wv.w * x2.w;
    a3 += wv.x * x3.x + wv.y * x3.y + wv.z * x3.z + wv.w * x3.w;
  }
  a0 += __shfl_xor(a0, 1); a0 += __shfl_xor(a0, 2);
  a1 += __shfl_xor(a1, 1); a1 += __shfl_xor(a1, 2);
  a2 += __shfl_xor(a2, 1); a2 += __shfl_xor(a2, 2);
  a3 += __shfl_xor(a3, 1); a3 += __shfl_xor(a3, 2);
  if ((t & 3) == 0) {
    const float bv = bias[f];
    out[(size_t)(bt * 4 + 0) * E_ + f] = a0 + bv;
    out[(size_t)(bt * 4 + 1) * E_ + f] = a1 + bv;
    out[(size_t)(bt * 4 + 2) * E_ + f] = a2 + bv;
    out[(size_t)(bt * 4 + 3) * E_ + f] = a3 + bv;
  }
}

// ---------------- LayerNorm + ReLU + L2-normalize for the 64 CLS rows ----------------
__global__ __launch_bounds__(256) void ln_relu_norm(const float* __restrict__ p,
                                                    const float* __restrict__ gamma,
                                                    const float* __restrict__ beta,
                                                    float* __restrict__ user) {
  const int b = blockIdx.x, t = threadIdx.x;
  const int w = t >> 6, l = t & 63;
  const float4 v = ((const float4*)(p + (size_t)b * E_))[t];
  float s = v.x + v.y + v.z + v.w;
  float s2 = v.x * v.x + v.y * v.y + v.z * v.z + v.w * v.w;
#pragma unroll
  for (int o = 1; o < 64; o <<= 1) { s += __shfl_xor(s, o); s2 += __shfl_xor(s2, o); }
  __shared__ float ss[4], ss2[4], qs[4];
  if (l == 0) { ss[w] = s; ss2[w] = s2; }
  __syncthreads();
  s = ss[0] + ss[1] + ss[2] + ss[3];
  s2 = ss2[0] + ss2[1] + ss2[2] + ss2[3];
  const float mu = s * (1.f / E_);
  const float var = s2 * (1.f / E_) - mu * mu;
  const float rstd = rsqrtf(var + 1e-5f);
  const float4 g = ((const float4*)gamma)[t];
  const float4 be = ((const float4*)beta)[t];
  float4 o;
  o.x = fmaxf((v.x - mu) * rstd * g.x + be.x, 0.f);
  o.y = fmaxf((v.y - mu) * rstd * g.y + be.y, 0.f);
  o.z = fmaxf((v.z - mu) * rstd * g.z + be.z, 0.f);
  o.w = fmaxf((v.w - mu) * rstd * g.w + be.w, 0.f);
  float q2 = o.x * o.x + o.y * o.y + o.z * o.z + o.w * o.w;
#pragma unroll
  for (int off = 1; off < 64; off <<= 1) q2 += __shfl_xor(q2, off);
  if (l == 0) qs[w] = q2;
  __syncthreads();
  q2 = qs[0] + qs[1] + qs[2] + qs[3];
  const float nrm = fmaxf(sqrtf(q2), 1e-12f);
  const float inv = 1.f / nrm;
  float4 u;
  u.x = o.x * inv; u.y = o.y * inv; u.z = o.z * inv; u.w = o.w * inv;
  ((float4*)(user + (size_t)b * E_))[t] = u;
}

extern "C" void kernel_launch(void* const* d_in, const int* in_sizes, int n_in,
                              void* d_out, int out_size, void* d_ws, size_t ws_size,
                              hipStream_t stream) {
  const float* news   = (const float*)d_in[0];
  const void*  maskp  = d_in[1];
  const float* cls    = (const float*)d_in[2];
  const float* pos    = (const float*)d_in[3];
  const float* w_in   = (const float*)d_in[4];
  const float* b_in   = (const float*)d_in[5];
  const float* w_out  = (const float*)d_in[6];
  const float* b_out  = (const float*)d_in[7];
  const float* w_proj = (const float*)d_in[8];
  const float* b_proj = (const float*)d_in[9];
  const float* gamma  = (const float*)d_in[10];
  const float* beta   = (const float*)d_in[11];

  char* ws = (char*)d_ws;
  // workspace layout (total ~143.5 MB)
  u16*  w_bf  = (u16*)(ws + 0);             //   6,291,456 B  (in_proj_w bf16)
  u16*  x_bf  = (u16*)(ws + 6291456);       //  34,078,720 B  (x bf16, MP2 x E_)
  u16*  qkv   = (u16*)(ws + 40370176);      // 102,236,160 B  (qkv bf16, MP2 x 3E)
  float* ctx  = (float*)(ws + 142606336);   //     262,144 B
  float* aoc  = (float*)(ws + 142868480);   //     262,144 B
  float* pcls = (float*)(ws + 143130624);   //     262,144 B
  int*  maskw = (int*)(ws + 143392768);     //      65,536 B

  float* user = (float*)d_out;
  float* attn = (float*)d_out + (size_t)B_ * E_;

  prep_w<<<3072, 256, 0, stream>>>(w_in, w_bf);
  build_x<<<MP2, 256, 0, stream>>>(news, cls, pos, x_bf);
  mask_prep<<<8, 256, 0, stream>>>(maskp, maskw);
  gemm_qkv<<<3120, 256, 0, stream>>>(x_bf, w_bf, b_in, qkv);
  attn_kernel<<<dim3(5, H_, B_), 256, 0, stream>>>(qkv, maskw, attn, ctx);
  gemv_cls<<<dim3(16, 16), 256, 0, stream>>>(ctx, w_out, b_out, aoc);
  gemv_cls<<<dim3(16, 16), 256, 0, stream>>>(aoc, w_proj, b_proj, pcls);
  ln_relu_norm<<<B_, 256, 0, stream>>>(pcls, gamma, beta, user);
}

// Round 19
// 344.590 us; speedup vs baseline: 1.0407x; 1.0107x over previous
//
#include <hip/hip_runtime.h>

// Problem constants
#define B_   64
#define N_   256
#define E_   1024
#define H_   16
#define D_   64
#define S_   257
#define M_   16448      // B_*S_
#define MP2  16640      // padded to 65*256 (=130*128)
#define N3_  3072
#define K_   1024

typedef unsigned short u16;
typedef unsigned int   u32;
typedef __bf16 bf16x8 __attribute__((ext_vector_type(8)));
typedef float  f32x4  __attribute__((ext_vector_type(4)));

__device__ inline u16 f2bf(float f) {
  union { float f; u32 u; } a; a.f = f;
  return (u16)((a.u + 0x7FFFu + ((a.u >> 16) & 1u)) >> 16);
}
__device__ inline float bf2f(u16 h) {
  union { u32 u; float f; } a; a.u = ((u32)h) << 16; return a.f;
}
__device__ inline void gload_lds16(const void* g, void* l) {
  __builtin_amdgcn_global_load_lds((const __attribute__((address_space(1))) void*)g,
                                   (__attribute__((address_space(3))) void*)l, 16, 0, 0);
}

// ---------------- prep: convert in_proj_w (3E x E) f32 -> bf16 ----------------
__global__ __launch_bounds__(256) void prep_w(const float* __restrict__ w, u16* __restrict__ o) {
  size_t i = ((size_t)blockIdx.x * 256 + threadIdx.x) * 4;
  float4 f = *(const float4*)(w + i);
  ushort4 v;
  v.x = f2bf(f.x); v.y = f2bf(f.y); v.z = f2bf(f.z); v.w = f2bf(f.w);
  *(ushort4*)(o + i) = v;
}

// ---------------- build x = concat(cls, news) + pos_emb, bf16, padded rows zeroed ----------------
__global__ __launch_bounds__(256) void build_x(const float* __restrict__ news,
                                               const float* __restrict__ cls,
                                               const float* __restrict__ pos,
                                               u16* __restrict__ x) {
  const int row = blockIdx.x;          // 0..16639
  const int e = threadIdx.x * 4;
  float4 v = make_float4(0.f, 0.f, 0.f, 0.f);
  if (row < M_) {
    const int b = row / S_;
    const int s = row - b * S_;
    float4 pe = *(const float4*)(pos + (size_t)s * E_ + e);
    float4 xv = (s == 0) ? *(const float4*)(cls + e)
                         : *(const float4*)(news + ((size_t)b * N_ + (s - 1)) * E_ + e);
    v.x = xv.x + pe.x; v.y = xv.y + pe.y; v.z = xv.z + pe.z; v.w = xv.w + pe.w;
  }
  ushort4 o;
  o.x = f2bf(v.x); o.y = f2bf(v.y); o.z = f2bf(v.z); o.w = f2bf(v.w);
  *(ushort4*)(x + (size_t)row * E_ + e) = o;
}

// ---------------- mask: detect dtype (int32 / uint8 / float32) -> int32 ----------------
__global__ __launch_bounds__(256) void mask_prep(const void* __restrict__ src, int* __restrict__ dst) {
  const int t = threadIdx.x;
  const u32* wsrc = (const u32*)src;
  u32 flag = 0;
  for (int i = t; i < 4096; i += 256) {       // detection window (same for all blocks)
    u32 v = wsrc[i];
    if (v == 0x3F800000u) flag |= 2u;
    else if (v > 1u) flag |= 1u;
  }
  __shared__ u32 fsh;
  if (t == 0) fsh = 0;
  __syncthreads();
  if (flag) atomicOr(&fsh, flag);
  __syncthreads();
  const u32 f = fsh;
  const int mode = (f & 2u) ? 2 : ((f & 1u) ? 1 : 0);
  const int base = blockIdx.x * 2048;
  for (int i = base + t; i < base + 2048; i += 256) {
    int m;
    if (mode == 0)      m = (wsrc[i] != 0u);
    else if (mode == 2) m = (((const float*)src)[i] != 0.f);
    else                m = (((const unsigned char*)src)[i] != 0);
    dst[i] = m;
  }
}

// ---------------- QKV GEMM: R9 measured-best (R3 body + XCD swizzle), verbatim ----------------
// 6/6 redesigns lost to this simple 128x128x32 row-major 2-__syncthreads loop at
// natural VGPR (~84) with bijective XCD swizzle. Do not touch.
__global__ __launch_bounds__(256) void gemm_qkv(const u16* __restrict__ A,
                                                const u16* __restrict__ Bw,
                                                const float* __restrict__ bias,
                                                u16* __restrict__ C) {
  __shared__ u16 As[128 * 32];
  __shared__ u16 Bs[128 * 32];
  const int t = threadIdx.x;
  const int w = t >> 6, l = t & 63;
  const int wr = w >> 1, wc = w & 1;

  const int orig = blockIdx.x;
  const int wgid = (orig & 7) * 390 + (orig >> 3);
  const int bm = wgid / 24, bn = wgid % 24;

  const u16* Ab = A + (size_t)bm * 128 * K_;
  const u16* Bb = Bw + (size_t)bn * 128 * K_;
  f32x4 acc[4][4] = {};
  const int r0 = t >> 2,         col0 = (t & 3) << 3;
  const int r1 = (256 + t) >> 2, col1 = ((256 + t) & 3) << 3;
  char* AsB = (char*)As + w * 1024;
  char* BsB = (char*)Bs + w * 1024;

  for (int k0 = 0; k0 < K_; k0 += 32) {
    gload_lds16(Ab + (size_t)r0 * K_ + k0 + col0, AsB);
    gload_lds16(Ab + (size_t)r1 * K_ + k0 + col1, AsB + 4096);
    gload_lds16(Bb + (size_t)r0 * K_ + k0 + col0, BsB);
    gload_lds16(Bb + (size_t)r1 * K_ + k0 + col1, BsB + 4096);
    __syncthreads();
    const int kc = (l >> 4) << 3;
    bf16x8 af[4], bfr[4];
#pragma unroll
    for (int m = 0; m < 4; ++m)
      af[m] = *(const bf16x8*)&As[(wr * 64 + m * 16 + (l & 15)) * 32 + kc];
#pragma unroll
    for (int n = 0; n < 4; ++n)
      bfr[n] = *(const bf16x8*)&Bs[(wc * 64 + n * 16 + (l & 15)) * 32 + kc];
#pragma unroll
    for (int m = 0; m < 4; ++m)
#pragma unroll
      for (int n = 0; n < 4; ++n)
        acc[m][n] = __builtin_amdgcn_mfma_f32_16x16x32_bf16(af[m], bfr[n], acc[m][n], 0, 0, 0);
    __syncthreads();
  }
  const int row0 = bm * 128 + wr * 64 + ((l >> 4) << 2);
  const int colb = bn * 128 + wc * 64 + (l & 15);
#pragma unroll
  for (int n = 0; n < 4; ++n) {
    const int col = colb + n * 16;
    const float bv = bias[col];
#pragma unroll
    for (int m = 0; m < 4; ++m) {
      const int row = row0 + m * 16;
#pragma unroll
      for (int j = 0; j < 4; ++j)
        C[(size_t)(row + j) * N3_ + col] = f2bf(acc[m][n][j] + bv);
    }
  }
}

// ---------------- attention: bf16-packed single pass + TWO-PHASE K staging (half LDS) ----------
// R15/R18 champion structure (non-swapped MFMA, pk[17][2] packed scores, sum of ROUNDED
// values) with ONE change: the 258-row K panel is staged in two phases through a single
// Ks[144x72] buffer (20.25KB vs 37.2KB) — phase A rows 0..143 (tiles 0..8), phase B rows
// 144..257 remapped to local 0..113 (zero clamp row at local 113; tiles 9..16).
// Total staged bytes unchanged; +2 barriers. LDS/block 40.4KB -> 23.9KB -> ~6 blocks/CU
// (24 waves, was ~12-16): attacks the diagnosed limiter (latency-bound at 34% occupancy).
__global__ __launch_bounds__(256) void attn_kernel(const u16* __restrict__ qkv,
                                                   const int* __restrict__ maskw,
                                                   float* __restrict__ attn,
                                                   float* __restrict__ ctx) {
  __shared__ u16 Ks[144 * 72];     // 20.25 KB, reused across two K-panel halves
  __shared__ float msk[272];       // keep-multiplier: 1=keep, 0=drop
  __shared__ float p0[272];        // normalized CLS row (qt==0 only)
  __shared__ float red[4][64];
  const int qt = blockIdx.x, h = blockIdx.y, b = blockIdx.z;
  const int t = threadIdx.x;
  const int q0 = qt * 64;

  // phase A: stage K rows 0..143 (all real rows; tiles 0..8)
  for (int c = t; c < 144 * 8; c += 256) {
    const int r = c >> 3, qq = c & 7;
    *(uint4*)&Ks[r * 72 + qq * 8] =
        *(const uint4*)(qkv + (size_t)(b * S_ + r) * N3_ + E_ + h * 64 + qq * 8);
  }
  // mask multipliers — ALL 272 entries (cols >= S_ must be 0)
  for (int i = t; i < 272; i += 256) {
    float m = 0.f;
    if (i == 0) m = 1.f;
    else if (i < S_) m = maskw[b * N_ + i - 1] ? 0.f : 1.f;
    msk[i] = m;
  }
  __syncthreads();

  const int w = t >> 6, l = t & 63;
  const int cl = l & 15, rg = l >> 4;
  const int kc = rg * 8;

  // Q fragment (loop-invariant) straight from global; row b*S_+q0+w*16+cl < MP2 rows
  const u16* qrow = qkv + (size_t)(b * S_ + q0 + w * 16 + cl) * N3_ + h * 64 + kc;
  const bf16x8 qa0 = *(const bf16x8*)qrow;
  const bf16x8 qa1 = *(const bf16x8*)(qrow + 32);

  u32 pk[17][2];                   // 34 VGPR: 4 bf16 exp values per kt tile
  float sum[4] = {0.f, 0.f, 0.f, 0.f};

  // ---- tiles 0..8 (rows 0..143, no clamp needed) ----
#pragma unroll
  for (int kt = 0; kt < 9; ++kt) {
    const u16* kb = &Ks[(kt * 16 + cl) * 72 + kc];
    f32x4 a = {0.f, 0.f, 0.f, 0.f};
    a = __builtin_amdgcn_mfma_f32_16x16x32_bf16(qa0, *(const bf16x8*)kb, a, 0, 0, 0);
    a = __builtin_amdgcn_mfma_f32_16x16x32_bf16(qa1, *(const bf16x8*)(kb + 32), a, 0, 0, 0);
    const float m = msk[kt * 16 + cl];
    u16 h0[4];
#pragma unroll
    for (int j = 0; j < 4; ++j) {
      h0[j] = f2bf(m * __expf(a[j] * 0.125f));
      sum[j] += bf2f(h0[j]);                       // sum of rounded values
    }
    pk[kt][0] = (u32)h0[0] | ((u32)h0[1] << 16);
    pk[kt][1] = (u32)h0[2] | ((u32)h0[3] << 16);
  }
  __syncthreads();                                  // all waves done reading phase A

  // phase B: stage K rows 144..257 at local 0..113 (local 113 = zeroed clamp row 257)
  for (int c = t; c < 114 * 8; c += 256) {
    const int r = c >> 3, qq = c & 7;
    const int g = 144 + r;
    uint4 val = make_uint4(0, 0, 0, 0);
    if (g < S_)
      val = *(const uint4*)(qkv + (size_t)(b * S_ + g) * N3_ + E_ + h * 64 + qq * 8);
    *(uint4*)&Ks[r * 72 + qq * 8] = val;
  }
  __syncthreads();

  // ---- tiles 9..16 (local row = min(kt*16+cl, 257) - 144) ----
#pragma unroll
  for (int kt = 9; kt < 17; ++kt) {
    int krow = kt * 16 + cl;
    if (krow > 257) krow = 257;
    const u16* kb = &Ks[(krow - 144) * 72 + kc];
    f32x4 a = {0.f, 0.f, 0.f, 0.f};
    a = __builtin_amdgcn_mfma_f32_16x16x32_bf16(qa0, *(const bf16x8*)kb, a, 0, 0, 0);
    a = __builtin_amdgcn_mfma_f32_16x16x32_bf16(qa1, *(const bf16x8*)(kb + 32), a, 0, 0, 0);
    const float m = msk[kt * 16 + cl];
    u16 h0[4];
#pragma unroll
    for (int j = 0; j < 4; ++j) {
      h0[j] = f2bf(m * __expf(a[j] * 0.125f));
      sum[j] += bf2f(h0[j]);
    }
    pk[kt][0] = (u32)h0[0] | ((u32)h0[1] << 16);
    pk[kt][1] = (u32)h0[2] | ((u32)h0[3] << 16);
  }

  float inv[4];
#pragma unroll
  for (int j = 0; j < 4; ++j) {
#pragma unroll
    for (int o = 1; o < 16; o <<= 1) sum[j] += __shfl_xor(sum[j], o);
    inv[j] = 1.f / sum[j];
  }

  // ---- unpack, scale, store ----
  const int qrow0 = q0 + w * 16 + rg * 4;
  float* abase = attn + (size_t)(b * H_ + h) * S_ * S_;
  const bool isCls = (qt == 0 && w == 0 && rg == 0);
#pragma unroll
  for (int j = 0; j < 4; ++j) {
    const int gq = qrow0 + j;
    if (gq < S_) {
      float* arow = abase + (size_t)gq * S_;
#pragma unroll
      for (int kt = 0; kt < 17; ++kt) {
        const int col = kt * 16 + cl;
        if (col < S_) {
          const u16 hh = (u16)(pk[kt][j >> 1] >> ((j & 1) * 16));
          arow[col] = bf2f(hh) * inv[j];
        }
      }
    }
  }
  if (isCls) {
#pragma unroll
    for (int kt = 0; kt < 17; ++kt) {
      const u16 hh = (u16)(pk[kt][0] & 0xFFFFu);   // j==0 value
      p0[kt * 16 + cl] = bf2f(hh) * inv[0];        // masked/pad cols -> 0
    }
  }

  // PV for the CLS row only (qt==0 blocks)
  if (qt == 0) {
    __syncthreads();
    const int part = t >> 6, d = t & 63;
    float acc = 0.f;
    for (int k = part; k < S_; k += 4)
      acc = fmaf(p0[k], bf2f(qkv[(size_t)(b * S_ + k) * N3_ + 2 * E_ + h * 64 + d]), acc);
    red[part][d] = acc;
    __syncthreads();
    if (t < 64)
      ctx[(size_t)b * E_ + h * 64 + t] = red[0][t] + red[1][t] + red[2][t] + red[3][t];
  }
}

// ---------------- GEMV for CLS rows: 256 blocks (full-chip), quad-per-row ----------------
__global__ __launch_bounds__(256) void gemv_cls(const float* __restrict__ in,
                                                const float* __restrict__ W,
                                                const float* __restrict__ bias,
                                                float* __restrict__ out) {
  const int bt = blockIdx.x, fc = blockIdx.y, t = threadIdx.x;
  __shared__ float xs[4][E_];
  for (int i = t; i < E_; i += 256)
    ((float4*)xs)[i] = ((const float4*)(in + (size_t)bt * 4 * E_))[i];
  __syncthreads();
  const int f = fc * 64 + (t >> 2);
  const int ec = (t & 3) * 256;
  const float4* wr = (const float4*)(W + (size_t)f * E_ + ec);
  float a0 = 0.f, a1 = 0.f, a2 = 0.f, a3 = 0.f;
#pragma unroll 8
  for (int e4 = 0; e4 < 64; ++e4) {
    const float4 wv = wr[e4];
    const float4 x0 = *(const float4*)&xs[0][ec + e4 * 4];
    const float4 x1 = *(const float4*)&xs[1][ec + e4 * 4];
    const float4 x2 = *(const float4*)&xs[2][ec + e4 * 4];
    const float4 x3 = *(const float4*)&xs[3][ec + e4 * 4];
    a0 += wv.x * x0.x + wv.y * x0.y + wv.z * x0.z + wv.w * x0.w;
    a1 += wv.x * x1.x + wv.y * x1.y + wv.z * x1.z + wv.w * x1.w;
    a2 += wv.x * x2.x + wv.y * x2.y + wv.z * x2.z + wv.w * x2.w;
    a3 += wv.x * x3.x + wv.y * x3.y + wv.z * x3.z + wv.w * x3.w;
  }
  a0 += __shfl_xor(a0, 1); a0 += __shfl_xor(a0, 2);
  a1 += __shfl_xor(a1, 1); a1 += __shfl_xor(a1, 2);
  a2 += __shfl_xor(a2, 1); a2 += __shfl_xor(a2, 2);
  a3 += __shfl_xor(a3, 1); a3 += __shfl_xor(a3, 2);
  if ((t & 3) == 0) {
    const float bv = bias[f];
    out[(size_t)(bt * 4 + 0) * E_ + f] = a0 + bv;
    out[(size_t)(bt * 4 + 1) * E_ + f] = a1 + bv;
    out[(size_t)(bt * 4 + 2) * E_ + f] = a2 + bv;
    out[(size_t)(bt * 4 + 3) * E_ + f] = a3 + bv;
  }
}

// ---------------- LayerNorm + ReLU + L2-normalize for the 64 CLS rows ----------------
__global__ __launch_bounds__(256) void ln_relu_norm(const float* __restrict__ p,
                                                    const float* __restrict__ gamma,
                                                    const float* __restrict__ beta,
                                                    float* __restrict__ user) {
  const int b = blockIdx.x, t = threadIdx.x;
  const int w = t >> 6, l = t & 63;
  const float4 v = ((const float4*)(p + (size_t)b * E_))[t];
  float s = v.x + v.y + v.z + v.w;
  float s2 = v.x * v.x + v.y * v.y + v.z * v.z + v.w * v.w;
#pragma unroll
  for (int o = 1; o < 64; o <<= 1) { s += __shfl_xor(s, o); s2 += __shfl_xor(s2, o); }
  __shared__ float ss[4], ss2[4], qs[4];
  if (l == 0) { ss[w] = s; ss2[w] = s2; }
  __syncthreads();
  s = ss[0] + ss[1] + ss[2] + ss[3];
  s2 = ss2[0] + ss2[1] + ss2[2] + ss2[3];
  const float mu = s * (1.f / E_);
  const float var = s2 * (1.f / E_) - mu * mu;
  const float rstd = rsqrtf(var + 1e-5f);
  const float4 g = ((const float4*)gamma)[t];
  const float4 be = ((const float4*)beta)[t];
  float4 o;
  o.x = fmaxf((v.x - mu) * rstd * g.x + be.x, 0.f);
  o.y = fmaxf((v.y - mu) * rstd * g.y + be.y, 0.f);
  o.z = fmaxf((v.z - mu) * rstd * g.z + be.z, 0.f);
  o.w = fmaxf((v.w - mu) * rstd * g.w + be.w, 0.f);
  float q2 = o.x * o.x + o.y * o.y + o.z * o.z + o.w * o.w;
#pragma unroll
  for (int off = 1; off < 64; off <<= 1) q2 += __shfl_xor(q2, off);
  if (l == 0) qs[w] = q2;
  __syncthreads();
  q2 = qs[0] + qs[1] + qs[2] + qs[3];
  const float nrm = fmaxf(sqrtf(q2), 1e-12f);
  const float inv = 1.f / nrm;
  float4 u;
  u.x = o.x * inv; u.y = o.y * inv; u.z = o.z * inv; u.w = o.w * inv;
  ((float4*)(user + (size_t)b * E_))[t] = u;
}

extern "C" void kernel_launch(void* const* d_in, const int* in_sizes, int n_in,
                              void* d_out, int out_size, void* d_ws, size_t ws_size,
                              hipStream_t stream) {
  const float* news   = (const float*)d_in[0];
  const void*  maskp  = d_in[1];
  const float* cls    = (const float*)d_in[2];
  const float* pos    = (const float*)d_in[3];
  const float* w_in   = (const float*)d_in[4];
  const float* b_in   = (const float*)d_in[5];
  const float* w_out  = (const float*)d_in[6];
  const float* b_out  = (const float*)d_in[7];
  const float* w_proj = (const float*)d_in[8];
  const float* b_proj = (const float*)d_in[9];
  const float* gamma  = (const float*)d_in[10];
  const float* beta   = (const float*)d_in[11];

  char* ws = (char*)d_ws;
  // workspace layout (total ~143.5 MB)
  u16*  w_bf  = (u16*)(ws + 0);             //   6,291,456 B  (in_proj_w bf16)
  u16*  x_bf  = (u16*)(ws + 6291456);       //  34,078,720 B  (x bf16, MP2 x E_)
  u16*  qkv   = (u16*)(ws + 40370176);      // 102,236,160 B  (qkv bf16, MP2 x 3E)
  float* ctx  = (float*)(ws + 142606336);   //     262,144 B
  float* aoc  = (float*)(ws + 142868480);   //     262,144 B
  float* pcls = (float*)(ws + 143130624);   //     262,144 B
  int*  maskw = (int*)(ws + 143392768);     //      65,536 B

  float* user = (float*)d_out;
  float* attn = (float*)d_out + (size_t)B_ * E_;

  prep_w<<<3072, 256, 0, stream>>>(w_in, w_bf);
  build_x<<<MP2, 256, 0, stream>>>(news, cls, pos, x_bf);
  mask_prep<<<8, 256, 0, stream>>>(maskp, maskw);
  gemm_qkv<<<3120, 256, 0, stream>>>(x_bf, w_bf, b_in, qkv);
  attn_kernel<<<dim3(5, H_, B_), 256, 0, stream>>>(qkv, maskw, attn, ctx);
  gemv_cls<<<dim3(16, 16), 256, 0, stream>>>(ctx, w_out, b_out, aoc);
  gemv_cls<<<dim3(16, 16), 256, 0, stream>>>(aoc, w_proj, b_proj, pcls);
  ln_relu_norm<<<B_, 256, 0, stream>>>(pcls, gamma, beta, user);
}